// Round 1
// baseline (600.909 us; speedup 1.0000x reference)
//
#include <hip/hip_runtime.h>

#define H 256
typedef unsigned int  uint;
typedef unsigned short ushort;
typedef float  floatx4 __attribute__((ext_vector_type(4)));
typedef short  shortx8 __attribute__((ext_vector_type(8)));

// ---- helpers ---------------------------------------------------------------
__device__ __forceinline__ ushort bf16rn(float f) {      // RNE f32->bf16
    uint u = __float_as_uint(f);
    u += 0x7FFF + ((u >> 16) & 1);
    return (ushort)(u >> 16);
}
__device__ __forceinline__ uint pkbf2(float a, float b) {
    return (uint)bf16rn(a) | ((uint)bf16rn(b) << 16);
}
__device__ __forceinline__ float bf2f(uint lo16) {       // low 16 bits = bf16
    return __uint_as_float(lo16 << 16);
}
// packed bf16x2 atomic add (global_atomic_pk_add_bf16, gfx940+) via asm
__device__ __forceinline__ void atomic_pk_bf16(void* addr, uint v) {
    asm volatile("global_atomic_pk_add_bf16 %0, %1, off" :: "v"(addr), "v"(v) : "memory");
}
// async global->LDS, 16B per lane. LDS dst = wave-uniform base + lane*16.
__device__ __forceinline__ void glds16(const void* g, void* l) {
    __builtin_amdgcn_global_load_lds(
        (__attribute__((address_space(1))) void*)(unsigned long long)(g),
        (__attribute__((address_space(3))) void*)(l), 16, 0, 0);
}

// ---------------------------------------------------------------------------
// W (512x256 f32, k-major) -> Wt (256x512 bf16, n-major) into d_ws (256KB)
// ---------------------------------------------------------------------------
__global__ __launch_bounds__(256) void wt_kernel(const float* __restrict__ W,
                                                 ushort* __restrict__ Wt) {
    int k = blockIdx.x;          // 0..511
    int n = threadIdx.x;         // 0..255
    Wt[(size_t)n * 512 + k] = bf16rn(W[(size_t)k * H + n]);
}

// ---------------------------------------------------------------------------
// prep: out row r := [ 512B zeros (agg accumulator, bf16) | 512B bf16(ns[r]) ]
// Replaces the memset AND gives scatter+GEMM a half-width A/ns read stream.
// ---------------------------------------------------------------------------
__global__ __launch_bounds__(256) void prep_kernel(const float* __restrict__ ns,
                                                   char* __restrict__ outbase, int M)
{
    int row = blockIdx.x * 2 + (threadIdx.x >> 7);
    if (row >= M) return;
    int t = threadIdx.x & 127;                       // column pair 0..127
    float2 v = ((const float2*)ns)[(size_t)row * 128 + t];
    uint* rp = (uint*)(outbase + (size_t)row * 1024);
    rp[t]       = 0u;                                // agg half = 0
    rp[128 + t] = pkbf2(v.x, v.y);                   // ns_bf16 half
}

// ---------------------------------------------------------------------------
// Scatter: 2 triples per 256-thread block; thread handles a column PAIR.
// ns rows are read as bf16 (512B) from the second half of the out rows ->
// hot read set = 50MB ns_bf16 + 100MB rs fp32, fits Infinity Cache.
// agg accumulated as bf16 packed into the FIRST 512B of each out row.
// ---------------------------------------------------------------------------
__global__ __launch_bounds__(256) void scatter_kernel(
    const float* __restrict__ rs, const int* __restrict__ trip,
    char* __restrict__ outbase, int n_trip)
{
    int t = blockIdx.x * 2 + (threadIdx.x >> 7);
    if (t >= n_trip) return;
    int p = threadIdx.x & 127;                       // column pair 0..127
    int s = trip[3 * t + 0];
    int r = trip[3 * t + 1];
    int o = trip[3 * t + 2];
    uint bs = *(const uint*)(outbase + (size_t)s * 1024 + 512 + p * 4);
    uint bo = *(const uint*)(outbase + (size_t)o * 1024 + 512 + p * 4);
    float2 vr = ((const float2*)rs)[(size_t)r * 128 + p];
    uint m_s2o = pkbf2(bf2f(bs & 0xffffu) + vr.x, bf2f(bs >> 16) + vr.y); // -> agg[o]
    uint m_o2s = pkbf2(bf2f(bo & 0xffffu) + vr.x, bf2f(bo >> 16) + vr.y); // -> agg[s]
    atomic_pk_bf16(outbase + (size_t)o * 1024 + p * 4, m_s2o);
    atomic_pk_bf16(outbase + (size_t)s * 1024 + p * 4, m_o2s);
}

// ---------------------------------------------------------------------------
// MFMA GEMM: out = ns + silu([ns|agg] @ W + b)
// Tile BM=64 x BN=256 x BK=32; 4 waves; wave w owns cols [64w,64w+64) as a
// 4x4 grid of 16x16x32 bf16 MFMA frags. A operand is bf16 in the out rows:
// k 0..255 = ns_bf16 (bytes [512,1024) of row), k 256..511 = agg (bytes
// [0,512)); both stream via global_load_lds. aoff = (512 + kt*64) & 1023.
// W via Wt (bf16 n-major), global_load_lds, stride-32 LDS.
// ---------------------------------------------------------------------------
__global__ __launch_bounds__(256) void gemm_kernel(
    const float* __restrict__ ns, const char* __restrict__ arows,
    const ushort* __restrict__ Wt, const float* __restrict__ bias,
    float* __restrict__ out, int M)
{
    __shared__ __align__(16) ushort As[64 * 32];    // A k-tile (bf16)
    __shared__ __align__(16) ushort Bs[256 * 32];   // Wt tile [n][k]

    const int tid  = threadIdx.x;
    const int wave = tid >> 6;
    const int lane = tid & 63;
    const int fm = lane & 15, fq = lane >> 4;       // frag row / quad
    const int rowBase = blockIdx.x * 64;

    floatx4 acc[4][4] = {};                          // [mi][ni]

    // staging maps: thread t -> tile row t>>2, k-quad t&3 (8 elems = 16B bf16)
    const int am = tid >> 2, akq = tid & 3;
    int arow = rowBase + am; if (arow >= M) arow = M - 1;
    const char* asrc = arows + (size_t)arow * 1024 + akq * 16;
    const char* wtp  = (const char*)Wt;

#pragma unroll
    for (int kt = 0; kt < 16; ++kt) {
        __syncthreads();
        glds16(asrc + ((512 + kt * 64) & 1023), &As[tid * 8]);
#pragma unroll
        for (int j = 0; j < 4; ++j)
            glds16(wtp + (size_t)(j * 64 + am) * 1024 + kt * 64 + akq * 16,
                   &Bs[j * 2048 + tid * 8]);
        __syncthreads();

        shortx8 aF[4], bF[4];
#pragma unroll
        for (int mi = 0; mi < 4; ++mi)
            aF[mi] = *(const shortx8*)&As[(mi * 16 + fm) * 32 + fq * 8];
#pragma unroll
        for (int ni = 0; ni < 4; ++ni)
            bF[ni] = *(const shortx8*)&Bs[(wave * 64 + ni * 16 + fm) * 32 + fq * 8];
#pragma unroll
        for (int mi = 0; mi < 4; ++mi)
#pragma unroll
            for (int ni = 0; ni < 4; ++ni)
                acc[mi][ni] = __builtin_amdgcn_mfma_f32_16x16x32_bf16(
                    aF[mi], bF[ni], acc[mi][ni], 0, 0, 0);
    }

    // ---------------- epilogue: bias + SiLU + residual ---------------------
    // C/D layout: col = lane&15, row = (lane>>4)*4 + reg  [m89/m91 verified]
#pragma unroll
    for (int mi = 0; mi < 4; ++mi) {
#pragma unroll
        for (int ni = 0; ni < 4; ++ni) {
            int col = wave * 64 + ni * 16 + fm;
            float bc = bias[col];
#pragma unroll
            for (int r = 0; r < 4; ++r) {
                int row = rowBase + mi * 16 + fq * 4 + r;
                if (row < M) {
                    float x = acc[mi][ni][r] + bc;
                    float sg = 1.f / (1.f + __expf(-x));
                    out[(size_t)row * H + col] = ns[(size_t)row * H + col] + x * sg;
                }
            }
        }
    }
}

extern "C" void kernel_launch(void* const* d_in, const int* in_sizes, int n_in,
                              void* d_out, int out_size, void* d_ws, size_t ws_size,
                              hipStream_t stream)
{
    const float* ns   = (const float*)d_in[0];
    const float* rs   = (const float*)d_in[1];
    const int*   tp   = (const int*)d_in[2];
    const float* Wm   = (const float*)d_in[3];
    const float* bias = (const float*)d_in[4];
    const int M      = in_sizes[0] / H;      // 100000
    const int n_trip = in_sizes[2] / 3;      // 300000
    float*  out = (float*)d_out;
    ushort* Wt  = (ushort*)d_ws;             // 256KB

    prep_kernel<<<dim3((M + 1) / 2), dim3(256), 0, stream>>>(ns, (char*)out, M);
    wt_kernel<<<dim3(512), dim3(256), 0, stream>>>(Wm, Wt);
    scatter_kernel<<<dim3((n_trip + 1) / 2), dim3(256), 0, stream>>>(
        rs, tp, (char*)out, n_trip);
    gemm_kernel<<<dim3((M + 63) / 64), dim3(256), 0, stream>>>(
        ns, (const char*)out, Wt, bias, out, M);
}

// Round 2
// 583.239 us; speedup vs baseline: 1.0303x; 1.0303x over previous
//
#include <hip/hip_runtime.h>

#define H 256
typedef unsigned int  uint;
typedef unsigned short ushort;
typedef float  floatx4 __attribute__((ext_vector_type(4)));
typedef short  shortx8 __attribute__((ext_vector_type(8)));

// ---- helpers ---------------------------------------------------------------
__device__ __forceinline__ ushort bf16rn(float f) {      // RNE f32->bf16
    uint u = __float_as_uint(f);
    u += 0x7FFF + ((u >> 16) & 1);
    return (ushort)(u >> 16);
}
__device__ __forceinline__ uint pkbf2(float a, float b) {
    return (uint)bf16rn(a) | ((uint)bf16rn(b) << 16);
}
__device__ __forceinline__ float bf2f(uint lo16) {       // low 16 bits = bf16
    return __uint_as_float(lo16 << 16);
}
// packed bf16x2 atomic add (global_atomic_pk_add_bf16, gfx940+) via asm
__device__ __forceinline__ void atomic_pk_bf16(void* addr, uint v) {
    asm volatile("global_atomic_pk_add_bf16 %0, %1, off" :: "v"(addr), "v"(v) : "memory");
}
// async global->LDS, 16B per lane. LDS dst = wave-uniform base + lane*16.
__device__ __forceinline__ void glds16(const void* g, void* l) {
    __builtin_amdgcn_global_load_lds(
        (__attribute__((address_space(1))) void*)(unsigned long long)(g),
        (__attribute__((address_space(3))) void*)(l), 16, 0, 0);
}

// ---------------------------------------------------------------------------
// W (512k x 256n f32, k-major) -> Wt (bf16, K-TILE-MAJOR: [kt][n][32])
// element (n,k) at ushort index ((k>>5)*256 + n)*32 + (k&31).
// Gives the GEMM fully contiguous 1KB-per-wave global_load_lds for B.
// Tiled transpose via LDS: coalesced reads AND writes.
// ---------------------------------------------------------------------------
__global__ __launch_bounds__(256) void wt_kernel(const float* __restrict__ W,
                                                 ushort* __restrict__ Wt) {
    __shared__ ushort tile[64][65];
    int k0 = (blockIdx.x >> 2) * 64;         // 8 k-tiles of 64
    int n0 = (blockIdx.x & 3) * 64;          // 4 n-tiles of 64
    int tx = threadIdx.x & 63, ty = threadIdx.x >> 6;
#pragma unroll
    for (int i = 0; i < 16; ++i) {
        int k = ty + i * 4;
        tile[k][tx] = bf16rn(W[(size_t)(k0 + k) * H + n0 + tx]);
    }
    __syncthreads();
#pragma unroll
    for (int i = 0; i < 16; ++i) {
        int n = ty + i * 4;                  // local n
        int k = k0 + tx;                     // global k
        Wt[(size_t)((k >> 5) * 256 + n0 + n) * 32 + (k & 31)] = tile[tx][n];
    }
}

// ---------------------------------------------------------------------------
// prep: out row r := [ 512B zeros (agg accumulator, bf16) | 512B bf16(ns[r]) ]
// ---------------------------------------------------------------------------
__global__ __launch_bounds__(256) void prep_kernel(const float* __restrict__ ns,
                                                   char* __restrict__ outbase, int M)
{
    int row = blockIdx.x * 2 + (threadIdx.x >> 7);
    if (row >= M) return;
    int t = threadIdx.x & 127;                       // column pair 0..127
    float2 v = ((const float2*)ns)[(size_t)row * 128 + t];
    uint* rp = (uint*)(outbase + (size_t)row * 1024);
    rp[t]       = 0u;                                // agg half = 0
    rp[128 + t] = pkbf2(v.x, v.y);                   // ns_bf16 half
}

// ---------------------------------------------------------------------------
// Scatter: 2 triples per 256-thread block; thread handles a column PAIR.
// ns read as bf16 from out-row second halves; agg accumulated via pk-bf16
// atomics into out-row first halves. Atomic-pipe-bound (~128 ops/cyc).
// ---------------------------------------------------------------------------
__global__ __launch_bounds__(256) void scatter_kernel(
    const float* __restrict__ rs, const int* __restrict__ trip,
    char* __restrict__ outbase, int n_trip)
{
    int t = blockIdx.x * 2 + (threadIdx.x >> 7);
    if (t >= n_trip) return;
    int p = threadIdx.x & 127;                       // column pair 0..127
    int s = trip[3 * t + 0];
    int r = trip[3 * t + 1];
    int o = trip[3 * t + 2];
    uint bs = *(const uint*)(outbase + (size_t)s * 1024 + 512 + p * 4);
    uint bo = *(const uint*)(outbase + (size_t)o * 1024 + 512 + p * 4);
    float2 vr = ((const float2*)rs)[(size_t)r * 128 + p];
    uint m_s2o = pkbf2(bf2f(bs & 0xffffu) + vr.x, bf2f(bs >> 16) + vr.y); // -> agg[o]
    uint m_o2s = pkbf2(bf2f(bo & 0xffffu) + vr.x, bf2f(bo >> 16) + vr.y); // -> agg[s]
    atomic_pk_bf16(outbase + (size_t)o * 1024 + p * 4, m_s2o);
    atomic_pk_bf16(outbase + (size_t)s * 1024 + p * 4, m_o2s);
}

// ---------------------------------------------------------------------------
// MFMA GEMM: out = ns + silu([ns|agg] @ W + b)
// Tile BM=128 x BN=256 x BK=32; 512 threads = 8 waves (2m x 4n); per-wave
// 64x64 output as 4x4 16x16x32 bf16 frags. Double-buffered LDS, minimum
// 2-phase pipeline: STAGE(kt+1) issued BEFORE compute(kt); one
// __syncthreads (vmcnt+lgkm drain + barrier) per K-step.
// A: bf16 in out rows (k 0..255 = ns_bf16 @bytes[512,1024), k 256..511 =
// agg @bytes[0,512)); offset trick (512+kt*64)&1023. B: Wt k-tile-major,
// 1KB contiguous per wave per glds.
// ---------------------------------------------------------------------------
__global__ __launch_bounds__(512) void gemm_kernel(
    const float* __restrict__ ns, const char* __restrict__ arows,
    const ushort* __restrict__ Wt, const float* __restrict__ bias,
    float* __restrict__ out, int M)
{
    __shared__ __align__(16) ushort As[2][128 * 32];   // 2 x 8KB
    __shared__ __align__(16) ushort Bs[2][256 * 32];   // 2 x 16KB

    const int tid  = threadIdx.x;
    const int wave = tid >> 6;
    const int lane = tid & 63;
    const int fm = lane & 15, fq = lane >> 4;          // frag row / quad
    const int wm = wave >> 2, wn = wave & 3;           // wave grid 2m x 4n
    const int rowBase = blockIdx.x * 128;

    floatx4 acc[4][4] = {};                            // [mi][ni]

    // staging map: thread t -> row t>>2 (0..127), k-quarter t&3 (16B)
    const int am = tid >> 2, akq = tid & 3;
    int arow = rowBase + am; if (arow >= M) arow = M - 1;
    const char* asrc = arows + (size_t)arow * 1024 + akq * 16;
    const char* wtp  = (const char*)Wt;

#define STAGE(kt, buf)                                                        \
    do {                                                                      \
        glds16(asrc + ((512 + (kt) * 64) & 1023), &As[(buf)][tid * 8]);       \
        glds16(wtp + (size_t)(kt) * 16384 + tid * 16, &Bs[(buf)][tid * 8]);   \
        glds16(wtp + (size_t)(kt) * 16384 + 8192 + tid * 16,                  \
               &Bs[(buf)][4096 + tid * 8]);                                   \
    } while (0)

    STAGE(0, 0);
    __syncthreads();                                   // drain prologue stage

#pragma unroll
    for (int kt = 0; kt < 16; ++kt) {
        const int cur = kt & 1;
        if (kt < 15) STAGE(kt + 1, cur ^ 1);           // overlap w/ compute

        shortx8 aF[4], bF[4];
#pragma unroll
        for (int mi = 0; mi < 4; ++mi)
            aF[mi] = *(const shortx8*)&As[cur][(wm * 64 + mi * 16 + fm) * 32 + fq * 8];
#pragma unroll
        for (int ni = 0; ni < 4; ++ni)
            bF[ni] = *(const shortx8*)&Bs[cur][(wn * 64 + ni * 16 + fm) * 32 + fq * 8];
#pragma unroll
        for (int mi = 0; mi < 4; ++mi)
#pragma unroll
            for (int ni = 0; ni < 4; ++ni)
                acc[mi][ni] = __builtin_amdgcn_mfma_f32_16x16x32_bf16(
                    aF[mi], bF[ni], acc[mi][ni], 0, 0, 0);

        __syncthreads();                               // drain stage kt+1, flip
    }
#undef STAGE

    // ---------------- epilogue: bias + SiLU + residual ---------------------
    // C/D layout: col = lane&15, row = (lane>>4)*4 + reg  [m89/m91 verified]
#pragma unroll
    for (int mi = 0; mi < 4; ++mi) {
#pragma unroll
        for (int ni = 0; ni < 4; ++ni) {
            int col = wn * 64 + ni * 16 + fm;
            float bc = bias[col];
#pragma unroll
            for (int r = 0; r < 4; ++r) {
                int row = rowBase + wm * 64 + mi * 16 + fq * 4 + r;
                if (row < M) {
                    float x = acc[mi][ni][r] + bc;
                    float sg = 1.f / (1.f + __expf(-x));
                    out[(size_t)row * H + col] = ns[(size_t)row * H + col] + x * sg;
                }
            }
        }
    }
}

extern "C" void kernel_launch(void* const* d_in, const int* in_sizes, int n_in,
                              void* d_out, int out_size, void* d_ws, size_t ws_size,
                              hipStream_t stream)
{
    const float* ns   = (const float*)d_in[0];
    const float* rs   = (const float*)d_in[1];
    const int*   tp   = (const int*)d_in[2];
    const float* Wm   = (const float*)d_in[3];
    const float* bias = (const float*)d_in[4];
    const int M      = in_sizes[0] / H;      // 100000
    const int n_trip = in_sizes[2] / 3;      // 300000
    float*  out = (float*)d_out;
    ushort* Wt  = (ushort*)d_ws;             // 256KB

    prep_kernel<<<dim3((M + 1) / 2), dim3(256), 0, stream>>>(ns, (char*)out, M);
    wt_kernel<<<dim3(32), dim3(256), 0, stream>>>(Wm, Wt);
    scatter_kernel<<<dim3((n_trip + 1) / 2), dim3(256), 0, stream>>>(
        rs, tp, (char*)out, n_trip);
    gemm_kernel<<<dim3((M + 127) / 128), dim3(512), 0, stream>>>(
        ns, (const char*)out, Wt, bias, out, M);
}

// Round 3
// 514.469 us; speedup vs baseline: 1.1680x; 1.1337x over previous
//
#include <hip/hip_runtime.h>

#define H 256
typedef unsigned int  uint;
typedef unsigned short ushort;
typedef float  floatx4 __attribute__((ext_vector_type(4)));
typedef short  shortx8 __attribute__((ext_vector_type(8)));

// ---- helpers ---------------------------------------------------------------
__device__ __forceinline__ ushort bf16rn(float f) {      // RNE f32->bf16
    uint u = __float_as_uint(f);
    u += 0x7FFF + ((u >> 16) & 1);
    return (ushort)(u >> 16);
}
__device__ __forceinline__ uint pkbf2(float a, float b) {
    return (uint)bf16rn(a) | ((uint)bf16rn(b) << 16);
}
__device__ __forceinline__ float bf2f(uint lo16) {       // low 16 bits = bf16
    return __uint_as_float(lo16 << 16);
}
// packed bf16x2 atomic add (global_atomic_pk_add_bf16, gfx940+) via asm
__device__ __forceinline__ void atomic_pk_bf16(void* addr, uint v) {
    asm volatile("global_atomic_pk_add_bf16 %0, %1, off" :: "v"(addr), "v"(v) : "memory");
}
// async global->LDS, 16B per lane. LDS dst = wave-uniform base + lane*16.
__device__ __forceinline__ void glds16(const void* g, void* l) {
    __builtin_amdgcn_global_load_lds(
        (__attribute__((address_space(1))) void*)(unsigned long long)(g),
        (__attribute__((address_space(3))) void*)(l), 16, 0, 0);
}

// ---------------------------------------------------------------------------
// W (512k x 256n f32, k-major) -> Wt (bf16, K-TILE-MAJOR: [kt][n][32])
// element (n,k) at ushort index ((k>>5)*256 + n)*32 + (k&31).
// ---------------------------------------------------------------------------
__global__ __launch_bounds__(256) void wt_kernel(const float* __restrict__ W,
                                                 ushort* __restrict__ Wt) {
    __shared__ ushort tile[64][65];
    int k0 = (blockIdx.x >> 2) * 64;         // 8 k-tiles of 64
    int n0 = (blockIdx.x & 3) * 64;          // 4 n-tiles of 64
    int tx = threadIdx.x & 63, ty = threadIdx.x >> 6;
#pragma unroll
    for (int i = 0; i < 16; ++i) {
        int k = ty + i * 4;
        tile[k][tx] = bf16rn(W[(size_t)(k0 + k) * H + n0 + tx]);
    }
    __syncthreads();
#pragma unroll
    for (int i = 0; i < 16; ++i) {
        int n = ty + i * 4;                  // local n
        int k = k0 + tx;                     // global k
        Wt[(size_t)((k >> 5) * 256 + n0 + n) * 32 + (k & 31)] = tile[tx][n];
    }
}

// ---------------------------------------------------------------------------
// prep. csr mode: row = [512B bf16(ns) | 512B bucket slots (64 x 8B)]
//       fallback: row = [512B zeros (agg) | 512B bf16(ns)]   (round-2 layout)
// ---------------------------------------------------------------------------
__global__ __launch_bounds__(256) void prep_kernel(const float* __restrict__ ns,
                                                   char* __restrict__ outbase,
                                                   int M, int csr)
{
    int row = blockIdx.x * 2 + (threadIdx.x >> 7);
    if (row >= M) return;
    int t = threadIdx.x & 127;                       // column pair 0..127
    float2 v = ((const float2*)ns)[(size_t)row * 128 + t];
    uint* rp = (uint*)(outbase + (size_t)row * 1024);
    if (csr) {
        rp[t] = pkbf2(v.x, v.y);                     // ns_bf16 -> bytes [0,512)
    } else {
        rp[t]       = 0u;                            // agg half = 0
        rp[128 + t] = pkbf2(v.x, v.y);               // ns_bf16 half
    }
}

// ---------------------------------------------------------------------------
// fill: 1 thread/triple. Push (other,rel) into each endpoint's inline bucket
// (64 slots x 8B at row bytes [512,1024)). Counters live in ws. Overflow
// (cnt>64, P~1e-38 at mean degree 6) sets flag for exact fixup.
// ---------------------------------------------------------------------------
__global__ __launch_bounds__(256) void fill_kernel(const int* __restrict__ trip,
                                                   char* __restrict__ outbase,
                                                   uint* __restrict__ cnt,
                                                   uint* __restrict__ flag, int n_trip)
{
    int t = blockIdx.x * 256 + threadIdx.x;
    if (t >= n_trip) return;
    int s = trip[3 * t + 0];
    int r = trip[3 * t + 1];
    int o = trip[3 * t + 2];
    uint i0 = atomicAdd(&cnt[o], 1u);                // msg(s,r) -> agg[o]
    if (i0 < 64u) { int2 e; e.x = s; e.y = r;
        *(int2*)(outbase + (size_t)o * 1024 + 512 + (size_t)i0 * 8) = e; }
    else atomicExch(flag, 1u);
    uint i1 = atomicAdd(&cnt[s], 1u);                // msg(o,r) -> agg[s]
    if (i1 < 64u) { int2 e; e.x = o; e.y = r;
        *(int2*)(outbase + (size_t)s * 1024 + 512 + (size_t)i1 * 8) = e; }
    else atomicExch(flag, 1u);
}

// ---------------------------------------------------------------------------
// gather: 1 wave/node; lane owns 4 columns. fp32-accumulate
// bf16(ns[other]) + rs[rel] over the node's bucket, then ONE plain 512B
// bf16 store of agg over the consumed bucket region. No atomics.
// ---------------------------------------------------------------------------
__global__ __launch_bounds__(256) void gather_kernel(const float* __restrict__ rs,
                                                     char* __restrict__ outbase,
                                                     const uint* __restrict__ cnt, int M)
{
    int node = blockIdx.x * 4 + (threadIdx.x >> 6);
    if (node >= M) return;
    int l = threadIdx.x & 63;
    char* row = outbase + (size_t)node * 1024;
    uint c = cnt[node];
    float4 acc = {0.f, 0.f, 0.f, 0.f};
    if (c <= 64u) {
        for (uint e = 0; e < c; ++e) {
            int2 ed = *(const int2*)(row + 512 + (size_t)e * 8);   // uniform
            uint2 nb = *(const uint2*)(outbase + (size_t)ed.x * 1024 + l * 8);
            float4 vr = *(const float4*)((const char*)rs + (size_t)ed.y * 1024 + l * 16);
            acc.x += bf2f(nb.x & 0xffffu) + vr.x;
            acc.y += bf2f(nb.x >> 16)     + vr.y;
            acc.z += bf2f(nb.y & 0xffffu) + vr.z;
            acc.w += bf2f(nb.y >> 16)     + vr.w;
        }
    }                                                // overflow: zeros, fixup adds
    uint2 o2; o2.x = pkbf2(acc.x, acc.y); o2.y = pkbf2(acc.z, acc.w);
    *(uint2*)(row + 512 + l * 8) = o2;               // agg bf16 -> [512,1024)
}

// ---------------------------------------------------------------------------
// fixup: flag-gated exact recompute for overflowed buckets (never taken in
// practice; ~2us early-exit). Adds ALL messages of any dest with cnt>64 via
// pk-atomics into the agg region (gather wrote zeros there for such nodes).
// ---------------------------------------------------------------------------
__global__ __launch_bounds__(256) void fixup_kernel(
    const float* __restrict__ rs, const int* __restrict__ trip,
    char* __restrict__ outbase, const uint* __restrict__ cnt,
    const uint* __restrict__ flag, int n_trip)
{
    if (flag[0] == 0u) return;
    int t = blockIdx.x * 256 + threadIdx.x;
    if (t >= n_trip) return;
    int s = trip[3 * t + 0];
    int r = trip[3 * t + 1];
    int o = trip[3 * t + 2];
#pragma unroll 1
    for (int pass = 0; pass < 2; ++pass) {
        int dst = pass ? s : o, oth = pass ? o : s;
        if (cnt[dst] <= 64u) continue;
        for (int p = 0; p < 128; ++p) {
            uint nb = *(const uint*)(outbase + (size_t)oth * 1024 + p * 4);
            float2 vr = ((const float2*)rs)[(size_t)r * 128 + p];
            atomic_pk_bf16(outbase + (size_t)dst * 1024 + 512 + p * 4,
                           pkbf2(bf2f(nb & 0xffffu) + vr.x, bf2f(nb >> 16) + vr.y));
        }
    }
}

// ---------------------------------------------------------------------------
// fallback scatter (round-2 proven path): pk-bf16 atomics, ~250us.
// ---------------------------------------------------------------------------
__global__ __launch_bounds__(256) void scatter_kernel(
    const float* __restrict__ rs, const int* __restrict__ trip,
    char* __restrict__ outbase, int n_trip)
{
    int t = blockIdx.x * 2 + (threadIdx.x >> 7);
    if (t >= n_trip) return;
    int p = threadIdx.x & 127;                       // column pair 0..127
    int s = trip[3 * t + 0];
    int r = trip[3 * t + 1];
    int o = trip[3 * t + 2];
    uint bs = *(const uint*)(outbase + (size_t)s * 1024 + 512 + p * 4);
    uint bo = *(const uint*)(outbase + (size_t)o * 1024 + 512 + p * 4);
    float2 vr = ((const float2*)rs)[(size_t)r * 128 + p];
    uint m_s2o = pkbf2(bf2f(bs & 0xffffu) + vr.x, bf2f(bs >> 16) + vr.y);
    uint m_o2s = pkbf2(bf2f(bo & 0xffffu) + vr.x, bf2f(bo >> 16) + vr.y);
    atomic_pk_bf16(outbase + (size_t)o * 1024 + p * 4, m_s2o);
    atomic_pk_bf16(outbase + (size_t)s * 1024 + p * 4, m_o2s);
}

// ---------------------------------------------------------------------------
// MFMA GEMM: out = ns + silu([ns|agg] @ W + b)
// BM=128 x BN=256 x BK=32; 512 thr = 8 waves (2m x 4n); dbuf LDS 2-phase.
// A byte offset within row: (aswap + kt*64) & 1023.
//   csr mode  (aswap=0):   kt 0..7 = ns_bf16 @[0,512), kt 8..15 = agg @[512,1024)
//   fallback  (aswap=512): kt 0..7 = ns_bf16 @[512,1024), kt 8..15 = agg @[0,512)
// ---------------------------------------------------------------------------
__global__ __launch_bounds__(512) void gemm_kernel(
    const float* __restrict__ ns, const char* __restrict__ arows,
    const ushort* __restrict__ Wt, const float* __restrict__ bias,
    float* __restrict__ out, int M, int aswap)
{
    __shared__ __align__(16) ushort As[2][128 * 32];   // 2 x 8KB
    __shared__ __align__(16) ushort Bs[2][256 * 32];   // 2 x 16KB

    const int tid  = threadIdx.x;
    const int wave = tid >> 6;
    const int lane = tid & 63;
    const int fm = lane & 15, fq = lane >> 4;          // frag row / quad
    const int wm = wave >> 2, wn = wave & 3;           // wave grid 2m x 4n
    const int rowBase = blockIdx.x * 128;

    floatx4 acc[4][4] = {};                            // [mi][ni]

    const int am = tid >> 2, akq = tid & 3;
    int arow = rowBase + am; if (arow >= M) arow = M - 1;
    const char* asrc = arows + (size_t)arow * 1024 + akq * 16;
    const char* wtp  = (const char*)Wt;

#define STAGE(kt, buf)                                                        \
    do {                                                                      \
        glds16(asrc + ((aswap + (kt) * 64) & 1023), &As[(buf)][tid * 8]);     \
        glds16(wtp + (size_t)(kt) * 16384 + tid * 16, &Bs[(buf)][tid * 8]);   \
        glds16(wtp + (size_t)(kt) * 16384 + 8192 + tid * 16,                  \
               &Bs[(buf)][4096 + tid * 8]);                                   \
    } while (0)

    STAGE(0, 0);
    __syncthreads();                                   // drain prologue stage

#pragma unroll
    for (int kt = 0; kt < 16; ++kt) {
        const int cur = kt & 1;
        if (kt < 15) STAGE(kt + 1, cur ^ 1);           // overlap w/ compute

        shortx8 aF[4], bF[4];
#pragma unroll
        for (int mi = 0; mi < 4; ++mi)
            aF[mi] = *(const shortx8*)&As[cur][(wm * 64 + mi * 16 + fm) * 32 + fq * 8];
#pragma unroll
        for (int ni = 0; ni < 4; ++ni)
            bF[ni] = *(const shortx8*)&Bs[cur][(wn * 64 + ni * 16 + fm) * 32 + fq * 8];
#pragma unroll
        for (int mi = 0; mi < 4; ++mi)
#pragma unroll
            for (int ni = 0; ni < 4; ++ni)
                acc[mi][ni] = __builtin_amdgcn_mfma_f32_16x16x32_bf16(
                    aF[mi], bF[ni], acc[mi][ni], 0, 0, 0);

        __syncthreads();                               // drain stage kt+1, flip
    }
#undef STAGE

    // C/D layout: col = lane&15, row = (lane>>4)*4 + reg  [m89/m91 verified]
#pragma unroll
    for (int mi = 0; mi < 4; ++mi) {
#pragma unroll
        for (int ni = 0; ni < 4; ++ni) {
            int col = wn * 64 + ni * 16 + fm;
            float bc = bias[col];
#pragma unroll
            for (int r = 0; r < 4; ++r) {
                int row = rowBase + wm * 64 + mi * 16 + fq * 4 + r;
                if (row < M) {
                    float x = acc[mi][ni][r] + bc;
                    float sg = 1.f / (1.f + __expf(-x));
                    out[(size_t)row * H + col] = ns[(size_t)row * H + col] + x * sg;
                }
            }
        }
    }
}

extern "C" void kernel_launch(void* const* d_in, const int* in_sizes, int n_in,
                              void* d_out, int out_size, void* d_ws, size_t ws_size,
                              hipStream_t stream)
{
    const float* ns   = (const float*)d_in[0];
    const float* rs   = (const float*)d_in[1];
    const int*   tp   = (const int*)d_in[2];
    const float* Wm   = (const float*)d_in[3];
    const float* bias = (const float*)d_in[4];
    const int M      = in_sizes[0] / H;      // 100000
    const int n_trip = in_sizes[2] / 3;      // 300000
    float*  out = (float*)d_out;
    ushort* Wt  = (ushort*)d_ws;             // [0, 256KB)

    size_t ws_need = 256 * 1024 + (size_t)M * 4 + 4;
    if (ws_size >= ws_need) {
        // ---- bucketized gather path (no wide-atomic bottleneck) ----
        uint* cnt  = (uint*)((char*)d_ws + 256 * 1024);
        uint* flag = cnt + M;
        hipMemsetAsync(cnt, 0, (size_t)M * 4 + 4, stream);
        prep_kernel<<<dim3((M + 1) / 2), dim3(256), 0, stream>>>(ns, (char*)out, M, 1);
        wt_kernel<<<dim3(32), dim3(256), 0, stream>>>(Wm, Wt);
        fill_kernel<<<dim3((n_trip + 255) / 256), dim3(256), 0, stream>>>(
            tp, (char*)out, cnt, flag, n_trip);
        gather_kernel<<<dim3((M + 3) / 4), dim3(256), 0, stream>>>(
            rs, (char*)out, cnt, M);
        fixup_kernel<<<dim3((n_trip + 255) / 256), dim3(256), 0, stream>>>(
            rs, tp, (char*)out, cnt, flag, n_trip);
        gemm_kernel<<<dim3((M + 127) / 128), dim3(512), 0, stream>>>(
            ns, (const char*)out, Wt, bias, out, M, 0);
    } else {
        // ---- fallback: round-2 proven atomic path ----
        prep_kernel<<<dim3((M + 1) / 2), dim3(256), 0, stream>>>(ns, (char*)out, M, 0);
        wt_kernel<<<dim3(32), dim3(256), 0, stream>>>(Wm, Wt);
        scatter_kernel<<<dim3((n_trip + 1) / 2), dim3(256), 0, stream>>>(
            rs, tp, (char*)out, n_trip);
        gemm_kernel<<<dim3((M + 127) / 128), dim3(512), 0, stream>>>(
            ns, (const char*)out, Wt, bias, out, M, 512);
    }
}